// Round 5
// baseline (230.780 us; speedup 1.0000x reference)
//
#include <hip/hip_runtime.h>

// Problem constants (z: [16, 64, 64, 64] f32, codebook: [2048, 64] f32)
#define C_DIM   64
#define HW      4096        // H*W
#define NROWS   65536       // B*H*W
#define N_E     2048
#define N_ELEM  4194304     // B*C*H*W
// Output layout (flat): z_q_out 4194304 | loss 1 | perplexity 1 | indices 65536
#define OUT_LOSS_OFF 4194304
#define OUT_PPL_OFF  4194305
#define OUT_IDX_OFF  4194306

#define ROWS_B   256                 // rows per block (4 waves x 64 rows)
#define NTILE    (N_E / 16)          // 128 code tiles of 16 codes
#define TILE_F4  384                 // 6144 B per tile = 3 splits x 2 k2 x 64 lanes x 16B

typedef __attribute__((ext_vector_type(8))) short bf16x8;
typedef __attribute__((ext_vector_type(4))) float f32x4;

// round-to-nearest-even f32 -> bf16 bits
__device__ __forceinline__ unsigned short f2bf(float f) {
    unsigned u = __float_as_uint(f);
    return (unsigned short)((u + 0x7FFFu + ((u >> 16) & 1u)) >> 16);
}
__device__ __forceinline__ float bf2f(unsigned short b) {
    return __uint_as_float(((unsigned)b) << 16);
}

// ---------------------------------------------------------------------------
// Prep: split codebook f32 -> 3 bf16 terms, scattered into MFMA A-fragment
// order (unchanged from R4, proven): off = ((tile*3+s)*2+k2)*512 + lane*8 + i,
// tile=c>>4, k2=k>>5, lane=((k&31)>>3)*16 + (c&15), i=k&7.
// Also zeroes counts/loss (replaces the memset dispatch).
// ---------------------------------------------------------------------------
__global__ __launch_bounds__(256) void vq_prep(
    const float* __restrict__ cb, unsigned short* __restrict__ cbp,
    int* __restrict__ counts, float* __restrict__ loss_accum)
{
    const int u = blockIdx.x * 256 + threadIdx.x;   // [0, 131072)
    if (u < N_E) counts[u] = 0;
    if (u == 0)  *loss_accum = 0.f;
    const int c = u >> 6, k = u & 63;
    const float v = cb[u];                          // cb[c][k], coalesced
    const unsigned short s1 = f2bf(v);
    const float r1 = v - bf2f(s1);
    const unsigned short s2 = f2bf(r1);
    const float r2 = r1 - bf2f(s2);
    const unsigned short s3 = f2bf(r2);
    const int tile = c >> 4, k2 = k >> 5, kk = k & 31;
    const int lane = (kk >> 3) * 16 + (c & 15), i = kk & 7;
    const int base = ((tile * 3 + 0) * 2 + k2) * 512 + lane * 8 + i;
    cbp[base]        = s1;     // s stride = 2*512
    cbp[base + 1024] = s2;
    cbp[base + 2048] = s3;
}

#define M16(A_, B_, C_) __builtin_amdgcn_mfma_f32_16x16x32_bf16((A_), (B_), (C_), 0, 0, 0)

// 8 split-passes (sc,sz): (1,1)(1,2)(2,1)(2,2)(1,3)(3,1)(2,3)(3,2); only (3,3) dropped.
// AA = A-frag register pair array name (double-buffered), NT = n-tile literal.
#define PASS8(AA, ACC, NT)                                                      \
    ACC = M16(AA[0], zf[0][NT][0], ACC); ACC = M16(AA[1], zf[0][NT][1], ACC);   \
    ACC = M16(AA[0], zf[1][NT][0], ACC); ACC = M16(AA[1], zf[1][NT][1], ACC);   \
    ACC = M16(AA[2], zf[0][NT][0], ACC); ACC = M16(AA[3], zf[0][NT][1], ACC);   \
    ACC = M16(AA[2], zf[1][NT][0], ACC); ACC = M16(AA[3], zf[1][NT][1], ACC);   \
    ACC = M16(AA[0], zf[2][NT][0], ACC); ACC = M16(AA[1], zf[2][NT][1], ACC);   \
    ACC = M16(AA[4], zf[0][NT][0], ACC); ACC = M16(AA[5], zf[0][NT][1], ACC);   \
    ACC = M16(AA[2], zf[2][NT][0], ACC); ACC = M16(AA[3], zf[2][NT][1], ACC);   \
    ACC = M16(AA[4], zf[1][NT][0], ACC); ACC = M16(AA[5], zf[1][NT][1], ACC);

// A-frag index: AA[s*2+k2] == R4's A[s][k2]; cbbuf frag f at [f*64 + lane].

__global__ __launch_bounds__(256, 2) void vq_mfma(
    const float* __restrict__ z, const float* __restrict__ cb,
    const unsigned short* __restrict__ cbp, float* __restrict__ out,
    int* __restrict__ counts, float* __restrict__ loss_accum)
{
    __shared__ float4 cbbuf[2][TILE_F4];   // 12 KB double-buffered A-frags
    __shared__ int    sidx[ROWS_B];
    __shared__ float  wsum[4];

    const int tid  = threadIdx.x;
    const int lane = tid & 63;
    const int wv   = tid >> 6;            // 0..3
    const int l15  = lane & 15, lg = lane >> 4;
    const int row0 = blockIdx.x * ROWS_B; // 256 rows, same b for whole block
    const int b    = row0 >> 12;
    const int hw0  = row0 & 4095;
    const float* zb = z + (size_t)b * C_DIM * HW + hw0;

    // ---- build z B-fragments straight from global (no LDS transpose):
    // lane needs z[ch = k2*32 + lg*8 + i][row = wv*64 + nt*16 + l15];
    // per instr: 4 runs of 64B (16 consecutive rows) -> coalesced. One-time.
    bf16x8 zf[3][4][2];
#pragma unroll
    for (int nt = 0; nt < 4; ++nt) {
        const int row_l = wv * 64 + nt * 16 + l15;
#pragma unroll
        for (int k2 = 0; k2 < 2; ++k2) {
#pragma unroll
            for (int i = 0; i < 8; ++i) {
                float v = zb[(size_t)(k2 * 32 + lg * 8 + i) * HW + row_l];
                unsigned short s1 = f2bf(v);
                float r1 = v - bf2f(s1);
                unsigned short s2 = f2bf(r1);
                float r2 = r1 - bf2f(s2);
                zf[0][nt][k2][i] = (short)s1;
                zf[1][nt][k2][i] = (short)s2;
                zf[2][nt][k2][i] = (short)f2bf(r2);
            }
        }
    }

    // ---- prologue: stage tiles 0 and 1 into LDS, load A_cur = tile 0 ----
    const float4* cbp4 = (const float4*)cbp;
#pragma unroll
    for (int tt = 0; tt < 2; ++tt) {
        float4 p0 = cbp4[(size_t)tt * TILE_F4 + tid];
        cbbuf[tt][tid] = p0;
        if (tid < 128) {
            float4 p1 = cbp4[(size_t)tt * TILE_F4 + 256 + tid];
            cbbuf[tt][256 + tid] = p1;
        }
    }
    __syncthreads();

    bf16x8 Acur[6], Anxt[6];
    {
        const bf16x8* Ab = (const bf16x8*)&cbbuf[0][0];
#pragma unroll
        for (int f = 0; f < 6; ++f) Acur[f] = Ab[f * 64 + lane];
    }

    // ---- main loop: 128 tiles, 1 barrier/tile, A-frags reg-double-buffered,
    // LDS staged 2 tiles ahead so MFMAs never wait on post-barrier ds_reads ----
    float best0 = -3.4e38f, best1 = -3.4e38f, best2 = -3.4e38f, best3 = -3.4e38f;
    int   bi0 = 0, bi1 = 0, bi2 = 0, bi3 = 0;
    const f32x4 zero4 = {0.f, 0.f, 0.f, 0.f};

#pragma unroll 1
    for (int t = 0; t < NTILE; ++t) {
        // prefetch tile t+2 to regs (consumed by ds_write below)
        float4 q0 = {0,0,0,0}, q1 = {0,0,0,0};
        const bool pf = (t + 2 < NTILE);
        if (pf) {
            q0 = cbp4[(size_t)(t + 2) * TILE_F4 + tid];
            if (tid < 128) q1 = cbp4[(size_t)(t + 2) * TILE_F4 + 256 + tid];
        }
        // read tile t+1's A-frags (its LDS buffer completed last tile)
        if (t + 1 < NTILE) {
            const bf16x8* Ab = (const bf16x8*)&cbbuf[(t + 1) & 1][0];
#pragma unroll
            for (int f = 0; f < 6; ++f) Anxt[f] = Ab[f * 64 + lane];
        }

        // 64 MFMAs on Acur: 4 independent 16-deep acc chains
        f32x4 acc0 = zero4, acc1 = zero4, acc2 = zero4, acc3 = zero4;
        PASS8(Acur, acc0, 0)
        PASS8(Acur, acc1, 1)
        PASS8(Acur, acc2, 2)
        PASS8(Acur, acc3, 3)

        // D layout (m89, proven in R4): z-row = lane&15, code = t*16 + lg*4 + reg
        const int cbase = t * 16 + lg * 4;
#pragma unroll
        for (int r = 0; r < 4; ++r) {
            if (acc0[r] > best0) { best0 = acc0[r]; bi0 = cbase + r; }
            if (acc1[r] > best1) { best1 = acc1[r]; bi1 = cbase + r; }
            if (acc2[r] > best2) { best2 = acc2[r]; bi2 = cbase + r; }
            if (acc3[r] > best3) { best3 = acc3[r]; bi3 = cbase + r; }
        }

        // write tile t+2 into the buffer freed by this tile's reg-load
        if (pf) {
            cbbuf[t & 1][tid] = q0;
            if (tid < 128) cbbuf[t & 1][256 + tid] = q1;
        }
        __syncthreads();
        if (t + 1 < NTILE) {
#pragma unroll
            for (int f = 0; f < 6; ++f) Acur[f] = Anxt[f];
        }
    }

    // ---- merge across the 4 lane-groups (codes strided by lane>>4) ----
#pragma unroll
    for (int off = 16; off <= 32; off <<= 1) {
        float ob; int oi;
        ob = __shfl_xor(best0, off, 64); oi = __shfl_xor(bi0, off, 64);
        if (ob > best0 || (ob == best0 && oi < bi0)) { best0 = ob; bi0 = oi; }
        ob = __shfl_xor(best1, off, 64); oi = __shfl_xor(bi1, off, 64);
        if (ob > best1 || (ob == best1 && oi < bi1)) { best1 = ob; bi1 = oi; }
        ob = __shfl_xor(best2, off, 64); oi = __shfl_xor(bi2, off, 64);
        if (ob > best2 || (ob == best2 && oi < bi2)) { best2 = ob; bi2 = oi; }
        ob = __shfl_xor(best3, off, 64); oi = __shfl_xor(bi3, off, 64);
        if (ob > best3 || (ob == best3 && oi < bi3)) { best3 = ob; bi3 = oi; }
    }
    {
        // lane owns row wv*64 + lane; its n-tile is lg -> select that best
        const int ii = (lg == 0) ? bi0 : (lg == 1) ? bi1 : (lg == 2) ? bi2 : bi3;
        const int row_l = wv * 64 + lane;
        sidx[row_l] = ii;
        out[OUT_IDX_OFF + row0 + row_l] = (float)ii;
        atomicAdd(&counts[ii], 1);
    }
    __syncthreads();

    // ---- fused epilogue: gather cb[idx], ST-write, loss partial.
    // r = tid (256 rows), c4 = j; z re-read from global (coalesced 1KB runs).
    float* ob0 = out + (size_t)b * C_DIM * HW + hw0;
    float lsum = 0.f;
#pragma unroll
    for (int j = 0; j < 16; ++j) {
        const int c4 = j;
        const float4 q4 = *(const float4*)(cb + (size_t)sidx[tid] * C_DIM + c4 * 4);
#pragma unroll
        for (int q = 0; q < 4; ++q) {
            const int c = c4 * 4 + q;
            const float zv = zb[(size_t)c * HW + tid];
            const float qv = (q == 0) ? q4.x : (q == 1) ? q4.y : (q == 2) ? q4.z : q4.w;
            const float d = qv - zv;               // same fp order as reference ST
            lsum += d * d;
            ob0[(size_t)c * HW + tid] = zv + d;
        }
    }
    for (int off = 32; off > 0; off >>= 1) lsum += __shfl_down(lsum, off, 64);
    if (lane == 0) wsum[wv] = lsum;
    __syncthreads();
    if (tid == 0)
        atomicAdd(loss_accum, wsum[0] + wsum[1] + wsum[2] + wsum[3]);
}

// ---------------------------------------------------------------------------
// Finalize: perplexity from histogram + loss. Single block.
// ---------------------------------------------------------------------------
__global__ __launch_bounds__(256) void vq_finalize(
    const int* __restrict__ counts, const float* __restrict__ loss_accum,
    float* __restrict__ out)
{
    float h = 0.f;
    for (int e = threadIdx.x; e < N_E; e += 256) {
        float em = (float)counts[e] * (1.0f / (float)NROWS);
        h -= em * logf(em + 1e-10f);
    }
    for (int off = 32; off > 0; off >>= 1) h += __shfl_down(h, off, 64);
    __shared__ float hs[4];
    const int lane = threadIdx.x & 63, w = threadIdx.x >> 6;
    if (lane == 0) hs[w] = h;
    __syncthreads();
    if (threadIdx.x == 0) {
        float H = hs[0] + hs[1] + hs[2] + hs[3];
        float m = loss_accum[0] * (1.0f / (float)N_ELEM);
        out[OUT_LOSS_OFF] = 0.25f * m + m;   // BETA*mean + mean
        out[OUT_PPL_OFF]  = expf(H);
    }
}

extern "C" void kernel_launch(void* const* d_in, const int* in_sizes, int n_in,
                              void* d_out, int out_size, void* d_ws, size_t ws_size,
                              hipStream_t stream)
{
    const float* z  = (const float*)d_in[0];
    const float* cb = (const float*)d_in[1];
    float* out = (float*)d_out;

    // ws: counts[2048] int (8KB) | loss f32 | pad | cbp bf16 splits (768KB) @16KB
    int*            counts     = (int*)d_ws;
    float*          loss_accum = (float*)((char*)d_ws + N_E * sizeof(int));
    unsigned short* cbp        = (unsigned short*)((char*)d_ws + 16384);

    vq_prep<<<N_E * C_DIM / 256, 256, 0, stream>>>(cb, cbp, counts, loss_accum);
    vq_mfma<<<NROWS / ROWS_B, 256, 0, stream>>>(z, cb, cbp, out, counts, loss_accum);
    vq_finalize<<<1, 256, 0, stream>>>(counts, loss_accum, out);
}

// Round 6
// 170.078 us; speedup vs baseline: 1.3569x; 1.3569x over previous
//
#include <hip/hip_runtime.h>

// Problem constants (z: [16, 64, 64, 64] f32, codebook: [2048, 64] f32)
#define C_DIM   64
#define HW      4096        // H*W
#define NROWS   65536       // B*H*W
#define N_E     2048
#define N_ELEM  4194304     // B*C*H*W
// Output layout (flat): z_q_out 4194304 | loss 1 | perplexity 1 | indices 65536
#define OUT_LOSS_OFF 4194304
#define OUT_PPL_OFF  4194305
#define OUT_IDX_OFF  4194306

#define ROWS_B   128                 // rows per block (4 waves x 32) -> 512 blocks = 2/CU
#define NTILE    (N_E / 16)          // 128 code tiles of 16 codes
#define TILE_U   384                 // 16B units per tile (6 frags x 64 lanes)

typedef __attribute__((ext_vector_type(8))) short bf16x8;
typedef __attribute__((ext_vector_type(4))) float f32x4;

// round-to-nearest-even f32 -> bf16 bits
__device__ __forceinline__ unsigned short f2bf(float f) {
    unsigned u = __float_as_uint(f);
    return (unsigned short)((u + 0x7FFFu + ((u >> 16) & 1u)) >> 16);
}
__device__ __forceinline__ float bf2f(unsigned short b) {
    return __uint_as_float(((unsigned)b) << 16);
}

// ---------------------------------------------------------------------------
// Prep: split codebook f32 -> 3 bf16 terms, scattered into MFMA A-fragment
// order (unchanged since R4, proven): off = ((tile*3+s)*2+k2)*512 + lane*8 + i,
// tile=c>>4, k2=k>>5, lane=((k&31)>>3)*16 + (c&15), i=k&7.
// Also zeroes counts/loss (replaces the memset dispatch).
// ---------------------------------------------------------------------------
__global__ __launch_bounds__(256) void vq_prep(
    const float* __restrict__ cb, unsigned short* __restrict__ cbp,
    int* __restrict__ counts, float* __restrict__ loss_accum)
{
    const int u = blockIdx.x * 256 + threadIdx.x;   // [0, 131072)
    if (u < N_E) counts[u] = 0;
    if (u == 0)  *loss_accum = 0.f;
    const int c = u >> 6, k = u & 63;
    const float v = cb[u];                          // cb[c][k], coalesced
    const unsigned short s1 = f2bf(v);
    const float r1 = v - bf2f(s1);
    const unsigned short s2 = f2bf(r1);
    const float r2 = r1 - bf2f(s2);
    const unsigned short s3 = f2bf(r2);
    const int tile = c >> 4, k2 = k >> 5, kk = k & 31;
    const int lane = (kk >> 3) * 16 + (c & 15), i = kk & 7;
    const int base = ((tile * 3 + 0) * 2 + k2) * 512 + lane * 8 + i;
    cbp[base]        = s1;     // s stride = 2*512
    cbp[base + 1024] = s2;
    cbp[base + 2048] = s3;
}

#define M16(A_, B_, C_) __builtin_amdgcn_mfma_f32_16x16x32_bf16((A_), (B_), (C_), 0, 0, 0)

// 8 split-passes (sc,sz): (1,1)(1,2)(2,1)(2,2)(1,3)(3,1)(2,3)(3,2); only (3,3) dropped.
// AA[s*2+k2]; NT = n-tile literal.
#define PASS8(AA, ACC, NT)                                                      \
    ACC = M16(AA[0], zf[0][NT][0], ACC); ACC = M16(AA[1], zf[0][NT][1], ACC);   \
    ACC = M16(AA[0], zf[1][NT][0], ACC); ACC = M16(AA[1], zf[1][NT][1], ACC);   \
    ACC = M16(AA[2], zf[0][NT][0], ACC); ACC = M16(AA[3], zf[0][NT][1], ACC);   \
    ACC = M16(AA[2], zf[1][NT][0], ACC); ACC = M16(AA[3], zf[1][NT][1], ACC);   \
    ACC = M16(AA[0], zf[2][NT][0], ACC); ACC = M16(AA[1], zf[2][NT][1], ACC);   \
    ACC = M16(AA[4], zf[0][NT][0], ACC); ACC = M16(AA[5], zf[0][NT][1], ACC);   \
    ACC = M16(AA[2], zf[2][NT][0], ACC); ACC = M16(AA[3], zf[2][NT][1], ACC);   \
    ACC = M16(AA[4], zf[1][NT][0], ACC); ACC = M16(AA[5], zf[1][NT][1], ACC);

// per-tile compute on A-register set AA: 32 MFMAs + argmax update
#define COMPUTE_TILE(T_, AA)                                                    \
    {                                                                           \
        f32x4 acc0 = zero4, acc1 = zero4;                                       \
        PASS8(AA, acc0, 0)                                                      \
        PASS8(AA, acc1, 1)                                                      \
        const int cbase = (T_) * 16 + lg * 4;                                   \
        _Pragma("unroll")                                                       \
        for (int r = 0; r < 4; ++r) {                                           \
            if (acc0[r] > best0) { best0 = acc0[r]; bi0 = cbase + r; }          \
            if (acc1[r] > best1) { best1 = acc1[r]; bi1 = cbase + r; }          \
        }                                                                       \
    }

__global__ __launch_bounds__(256, 2) void vq_mfma(
    const float* __restrict__ z, const float* __restrict__ cb,
    const unsigned short* __restrict__ cbp, float* __restrict__ out,
    int* __restrict__ counts, float* __restrict__ loss_accum)
{
    __shared__ int   sidx[ROWS_B];
    __shared__ float wsum[4];

    const int tid  = threadIdx.x;
    const int lane = tid & 63;
    const int wv   = tid >> 6;            // 0..3
    const int l15  = lane & 15, lg = lane >> 4;
    const int row0 = blockIdx.x * ROWS_B; // 128 rows, same b for whole block
    const int b    = row0 >> 12;
    const int hw0  = row0 & 4095;
    const float* zb = z + (size_t)b * C_DIM * HW + hw0;

    // ---- build z B-fragments straight from global (coalesced 64B runs) ----
    bf16x8 zf[3][2][2];
#pragma unroll
    for (int nt = 0; nt < 2; ++nt) {
        const int row_l = wv * 32 + nt * 16 + l15;
#pragma unroll
        for (int k2 = 0; k2 < 2; ++k2) {
#pragma unroll
            for (int i = 0; i < 8; ++i) {
                float v = zb[(size_t)(k2 * 32 + lg * 8 + i) * HW + row_l];
                unsigned short s1 = f2bf(v);
                float r1 = v - bf2f(s1);
                unsigned short s2 = f2bf(r1);
                float r2 = r1 - bf2f(s2);
                zf[0][nt][k2][i] = (short)s1;
                zf[1][nt][k2][i] = (short)s2;
                zf[2][nt][k2][i] = (short)f2bf(r2);
            }
        }
    }

    // ---- main loop: no LDS, no barriers. Each wave streams its A-frags
    // global->VGPR from L2-resident cbp (768 KB), reg ping-pong 2 tiles deep:
    // tile t's 32 MFMAs (~620 SIMD-cyc) cover tile t+1's ~200-cyc L2 latency.
    const bf16x8* cbpf = (const bf16x8*)cbp;   // 16B units; tile t at [t*384]
    float best0 = -3.4e38f, best1 = -3.4e38f;
    int   bi0 = 0, bi1 = 0;
    const f32x4 zero4 = {0.f, 0.f, 0.f, 0.f};

    bf16x8 Acur[6], Anxt[6];
#pragma unroll
    for (int f = 0; f < 6; ++f) Acur[f] = cbpf[f * 64 + lane];

#pragma unroll 1
    for (int t = 0; t < NTILE; t += 2) {
        // issue loads for tile t+1 (always exists: NTILE even)
#pragma unroll
        for (int f = 0; f < 6; ++f)
            Anxt[f] = cbpf[(size_t)(t + 1) * TILE_U + f * 64 + lane];

        COMPUTE_TILE(t, Acur)

        // issue loads for tile t+2 into the registers tile t just freed
        if (t + 2 < NTILE) {
#pragma unroll
            for (int f = 0; f < 6; ++f)
                Acur[f] = cbpf[(size_t)(t + 2) * TILE_U + f * 64 + lane];
        }

        COMPUTE_TILE(t + 1, Anxt)
    }

    // ---- merge across the 4 lane-groups (codes strided by lane>>4) ----
#pragma unroll
    for (int off = 16; off <= 32; off <<= 1) {
        float ob; int oi;
        ob = __shfl_xor(best0, off, 64); oi = __shfl_xor(bi0, off, 64);
        if (ob > best0 || (ob == best0 && oi < bi0)) { best0 = ob; bi0 = oi; }
        ob = __shfl_xor(best1, off, 64); oi = __shfl_xor(bi1, off, 64);
        if (ob > best1 || (ob == best1 && oi < bi1)) { best1 = ob; bi1 = oi; }
    }
    if (lane < 32) {
        const int nt = lane >> 4;
        const int row_l = wv * 32 + lane;          // = wv*32 + nt*16 + l15
        const int ii = (nt == 0) ? bi0 : bi1;
        sidx[row_l] = ii;
        out[OUT_IDX_OFF + row0 + row_l] = (float)ii;
        atomicAdd(&counts[ii], 1);
    }
    __syncthreads();

    // ---- fused epilogue: gather cb[idx], ST-write, loss partial.
    // 2048 float4 units = 128 rows x 16 c4; z re-read from global (coalesced).
    float* ob0 = out + (size_t)b * C_DIM * HW + hw0;
    float lsum = 0.f;
#pragma unroll
    for (int j = 0; j < 8; ++j) {
        const int m = j * 256 + tid;               // [0,2048)
        const int r = m & 127, c4 = m >> 7;
        const float4 q4 = *(const float4*)(cb + (size_t)sidx[r] * C_DIM + c4 * 4);
#pragma unroll
        for (int q = 0; q < 4; ++q) {
            const int c = c4 * 4 + q;
            const float zv = zb[(size_t)c * HW + r];
            const float qv = (q == 0) ? q4.x : (q == 1) ? q4.y : (q == 2) ? q4.z : q4.w;
            const float d = qv - zv;               // same fp order as reference ST
            lsum += d * d;
            ob0[(size_t)c * HW + r] = zv + d;
        }
    }
    for (int off = 32; off > 0; off >>= 1) lsum += __shfl_down(lsum, off, 64);
    if (lane == 0) wsum[wv] = lsum;
    __syncthreads();
    if (tid == 0)
        atomicAdd(loss_accum, wsum[0] + wsum[1] + wsum[2] + wsum[3]);
}

// ---------------------------------------------------------------------------
// Finalize: perplexity from histogram + loss. Single block.
// ---------------------------------------------------------------------------
__global__ __launch_bounds__(256) void vq_finalize(
    const int* __restrict__ counts, const float* __restrict__ loss_accum,
    float* __restrict__ out)
{
    float h = 0.f;
    for (int e = threadIdx.x; e < N_E; e += 256) {
        float em = (float)counts[e] * (1.0f / (float)NROWS);
        h -= em * logf(em + 1e-10f);
    }
    for (int off = 32; off > 0; off >>= 1) h += __shfl_down(h, off, 64);
    __shared__ float hs[4];
    const int lane = threadIdx.x & 63, w = threadIdx.x >> 6;
    if (lane == 0) hs[w] = h;
    __syncthreads();
    if (threadIdx.x == 0) {
        float H = hs[0] + hs[1] + hs[2] + hs[3];
        float m = loss_accum[0] * (1.0f / (float)N_ELEM);
        out[OUT_LOSS_OFF] = 0.25f * m + m;   // BETA*mean + mean
        out[OUT_PPL_OFF]  = expf(H);
    }
}

extern "C" void kernel_launch(void* const* d_in, const int* in_sizes, int n_in,
                              void* d_out, int out_size, void* d_ws, size_t ws_size,
                              hipStream_t stream)
{
    const float* z  = (const float*)d_in[0];
    const float* cb = (const float*)d_in[1];
    float* out = (float*)d_out;

    // ws: counts[2048] int (8KB) | loss f32 | pad | cbp bf16 splits (768KB) @16KB
    int*            counts     = (int*)d_ws;
    float*          loss_accum = (float*)((char*)d_ws + N_E * sizeof(int));
    unsigned short* cbp        = (unsigned short*)((char*)d_ws + 16384);

    vq_prep<<<N_E * C_DIM / 256, 256, 0, stream>>>(cb, cbp, counts, loss_accum);
    vq_mfma<<<NROWS / ROWS_B, 256, 0, stream>>>(z, cb, cbp, out, counts, loss_accum);
    vq_finalize<<<1, 256, 0, stream>>>(counts, loss_accum, out);
}